// Round 8
// baseline (44.518 us; speedup 1.0000x reference)
//
#include <hip/hip_runtime.h>

typedef float v2f __attribute__((ext_vector_type(2)));
typedef float v4f __attribute__((ext_vector_type(4)));

#define IMG_H 384
#define IMG_W 512
#define RPT 8           // output rows per thread
#define TY  2           // thread strips per block (y)
#define NLX 128         // threads across x (128 lanes * 4 cols = 512 = full width)
#define RING 4          // raw-row ring; prefetch distance = 2 iterations (pinned)

struct Raw {
    float4 p, t;
    float pe, te;   // cross-wave edge value (valid only on the 2 lanes that need it)
};

struct RowH {
    v2f hx[4];      // (sum3_p, sum3_t) horizontal 3-tap for 4 outputs
    v2f hxx[4];     // (sum3_pp, sum3_tt)
    float hpt[4];   // sum3_pt
};

__device__ __forceinline__ int reflect_y(int gy) {
    if (gy < 0) gy = -gy;
    else if (gy >= IMG_H) gy = 2 * IMG_H - 2 - gy;
    return gy;
}

__device__ __forceinline__ Raw load_row(
    const float* __restrict__ pred, const float* __restrict__ target,
    size_t base, int ry, int col0, bool needE, int eoff)
{
    int gy = reflect_y(ry);
    const float* rp = pred   + base + (size_t)gy * IMG_W;
    const float* rt = target + base + (size_t)gy * IMG_W;
    Raw r;
    r.p = *(const float4*)(rp + col0);
    r.t = *(const float4*)(rt + col0);
    r.pe = 0.f; r.te = 0.f;
    if (needE) {            // only 2 lanes per wave active
        r.pe = rp[eoff];
        r.te = rt[eoff];
    }
    return r;
}

__device__ __forceinline__ RowH reduce_row(const Raw& r, int lane, int col0)
{
    // window cols 4lx-1 .. 4lx+4; edges from neighbor lanes via shuffle
    float x0p = __shfl_up(r.p.w, 1);
    float x0t = __shfl_up(r.t.w, 1);
    float x5p = __shfl_down(r.p.x, 1);
    float x5t = __shfl_down(r.t.x, 1);
    if (lane == 0) {
        if (col0 == 0) { x0p = r.p.y; x0t = r.t.y; }      // reflect col -1 -> 1
        else           { x0p = r.pe;  x0t = r.te;  }      // cross-wave boundary
    }
    if (lane == 63) {
        if (col0 + 4 == IMG_W) { x5p = r.p.z; x5t = r.t.z; }  // reflect col W -> W-2
        else                   { x5p = r.pe;  x5t = r.te;  }  // cross-wave boundary
    }

    v2f x0 = {x0p,   x0t};
    v2f x1 = {r.p.x, r.t.x};
    v2f x2 = {r.p.y, r.t.y};
    v2f x3 = {r.p.z, r.t.z};
    v2f x4 = {r.p.w, r.t.w};
    v2f x5 = {x5p,   x5t};

    RowH h;
    v2f a = x1 + x2, b = x3 + x4;
    h.hx[0] = x0 + a;  h.hx[1] = a + x3;
    h.hx[2] = x2 + b;  h.hx[3] = b + x5;

    v2f q0 = x0*x0, q1 = x1*x1, q2 = x2*x2, q3 = x3*x3, q4 = x4*x4, q5 = x5*x5;
    v2f aq = q1 + q2, bq = q3 + q4;
    h.hxx[0] = q0 + aq;  h.hxx[1] = aq + q3;
    h.hxx[2] = q2 + bq;  h.hxx[3] = bq + q5;

    float m0 = x0.x*x0.y, m1 = x1.x*x1.y, m2 = x2.x*x2.y,
          m3 = x3.x*x3.y, m4 = x4.x*x4.y, m5 = x5.x*x5.y;
    float am = m1 + m2, bm = m3 + m4;
    h.hpt[0] = m0 + am;  h.hpt[1] = am + m3;
    h.hpt[2] = m2 + bm;  h.hpt[3] = bm + m5;
    return h;
}

__device__ __forceinline__ void emit_row(
    float* __restrict__ out, size_t base, int row, int col0,
    const RowH& A, const RowH& B, const RowH& C)
{
    const float C1 = 1e-4f;    // 0.01^2
    const float C2 = 9e-4f;    // 0.03^2
    const float inv9 = 1.0f / 9.0f;

    v4f rv;
    #pragma unroll
    for (int j = 0; j < 4; ++j) {
        v2f sx  = A.hx[j]  + B.hx[j]  + C.hx[j];
        v2f sxx = A.hxx[j] + B.hxx[j] + C.hxx[j];
        float spt = A.hpt[j] + B.hpt[j] + C.hpt[j];

        v2f u  = sx * inv9;
        v2f uu = u * u;
        v2f sig = sxx * inv9 - uu;
        float upt   = u.x * u.y;
        float sigco = fmaf(spt, inv9, -upt);

        float num = fmaf(2.f, upt, C1) * fmaf(2.f, sigco, C2);
        float den = (uu.x + uu.y + C1) * (sig.x + sig.y + C2);
        float q = num * __builtin_amdgcn_rcpf(den);
        rv[j] = fminf(fmaxf(fmaf(q, -0.5f, 0.5f), 0.f), 1.f);
    }
    __builtin_nontemporal_store(rv, (v4f*)(out + base + (size_t)row * IMG_W + col0));
}

__global__ __launch_bounds__(NLX * TY) void ssim_kernel(
    const float* __restrict__ pred,
    const float* __restrict__ target,
    float* __restrict__ out)
{
    const int lx   = threadIdx.x;            // 0..127
    const int lane = lx & 63;
    const int col0 = 4 * lx;
    const size_t base = (size_t)blockIdx.z * (IMG_H * IMG_W);
    const int y0 = (blockIdx.y * TY + threadIdx.y) * RPT;

    const bool needL = (lane == 0)  && (col0 != 0);          // needs col0-1 across wave
    const bool needR = (lane == 63) && (col0 + 4 != IMG_W);  // needs col0+4 across wave
    const bool needE = needL || needR;
    const int  eoff  = needL ? (col0 - 1) : (col0 + 4);

    Raw  raw[RING];
    RowH h[3];

    // prologue: rows k=0..3 (ry = y0-1 .. y0+2) in flight
    #pragma unroll
    for (int k = 0; k < RING; ++k)
        raw[k] = load_row(pred, target, base, y0 - 1 + k, col0, needE, eoff);
    __builtin_amdgcn_sched_barrier(0);   // pin: all 4 row-loads issued before any compute

    h[0] = reduce_row(raw[0], lane, col0);
    h[1] = reduce_row(raw[1], lane, col0);

    // iter r: prefetch row k=r+4 (consumed at iter r+2), reduce k=r+2, emit row y0+r
    #pragma unroll
    for (int r = 0; r < RPT; ++r) {
        if (r <= RPT - 3)
            raw[r % RING] = load_row(pred, target, base, y0 + r + 3, col0, needE, eoff);
        __builtin_amdgcn_sched_barrier(0);   // loads stay issued ABOVE this point
        h[(r + 2) % 3] = reduce_row(raw[(r + 2) % RING], lane, col0);
        emit_row(out, base, y0 + r, col0, h[r % 3], h[(r + 1) % 3], h[(r + 2) % 3]);
    }
}

extern "C" void kernel_launch(void* const* d_in, const int* in_sizes, int n_in,
                              void* d_out, int out_size, void* d_ws, size_t ws_size,
                              hipStream_t stream) {
    const float* pred   = (const float*)d_in[0];
    const float* target = (const float*)d_in[1];
    float* out = (float*)d_out;

    const int planes = in_sizes[0] / (IMG_H * IMG_W);   // 32*3 = 96

    dim3 block(NLX, TY);                                 // 256 threads
    dim3 grid(1, IMG_H / (TY * RPT), planes);            // (1, 24, 96)
    ssim_kernel<<<grid, block, 0, stream>>>(pred, target, out);
}

// Round 9
// 42.569 us; speedup vs baseline: 1.0458x; 1.0458x over previous
//
#include <hip/hip_runtime.h>

typedef float v2f __attribute__((ext_vector_type(2)));
typedef float v4f __attribute__((ext_vector_type(4)));

#define IMG_H 384
#define IMG_W 512
#define RPT 8           // output rows per thread
#define TY  2           // strips per block
#define NLX 128         // lanes across x (128 * 4 cols = 512)

struct Raw  { v4f p, t; float pe, te; };
struct RowH { v2f hx[4]; v2f hxx[4]; float hpt[4]; };

__device__ __forceinline__ int reflect_y(int gy) {
    if (gy < 0) gy = -gy;
    else if (gy >= IMG_H) gy = 2 * IMG_H - 2 - gy;
    return gy;
}

// Issue one row's loads into ring slot S. Volatile asm: cannot be sunk/collapsed.
#define ISSUE(S, RY) do {                                                          \
    int gy_ = reflect_y(RY);                                                       \
    const float* rp_ = pred   + base + (size_t)gy_ * IMG_W;                        \
    const float* rt_ = target + base + (size_t)gy_ * IMG_W;                        \
    asm volatile("global_load_dwordx4 %0, %1, off" : "=v"(raw##S.p)  : "v"(rp_ + col0)); \
    asm volatile("global_load_dwordx4 %0, %1, off" : "=v"(raw##S.t)  : "v"(rt_ + col0)); \
    asm volatile("global_load_dword %0, %1, off"   : "=v"(raw##S.pe) : "v"(rp_ + eoff)); \
    asm volatile("global_load_dword %0, %1, off"   : "=v"(raw##S.te) : "v"(rt_ + eoff)); \
} while (0)

// Counted wait + scheduling fence (rule #18: fence AFTER the waitcnt).
#define WAITV(N) do {                                                              \
    asm volatile("s_waitcnt vmcnt(" #N ")" ::: "memory");                          \
    __builtin_amdgcn_sched_barrier(0);                                             \
} while (0)

__device__ __forceinline__ RowH reduce_row(const Raw& r, int lane, int col0)
{
    // window cols 4lx-1 .. 4lx+4; edges from neighbor lanes via shuffle
    float x0p = __shfl_up(r.p.w, 1);
    float x0t = __shfl_up(r.t.w, 1);
    float x5p = __shfl_down(r.p.x, 1);
    float x5t = __shfl_down(r.t.x, 1);
    if (lane == 0) {
        if (col0 == 0) { x0p = r.p.y; x0t = r.t.y; }      // reflect col -1 -> 1
        else           { x0p = r.pe;  x0t = r.te;  }      // cross-wave boundary
    }
    if (lane == 63) {
        if (col0 + 4 == IMG_W) { x5p = r.p.z; x5t = r.t.z; }  // reflect col W -> W-2
        else                   { x5p = r.pe;  x5t = r.te;  }  // cross-wave boundary
    }

    v2f x0 = {x0p,   x0t};
    v2f x1 = {r.p.x, r.t.x};
    v2f x2 = {r.p.y, r.t.y};
    v2f x3 = {r.p.z, r.t.z};
    v2f x4 = {r.p.w, r.t.w};
    v2f x5 = {x5p,   x5t};

    RowH h;
    v2f a = x1 + x2, b = x3 + x4;
    h.hx[0] = x0 + a;  h.hx[1] = a + x3;
    h.hx[2] = x2 + b;  h.hx[3] = b + x5;

    v2f q0 = x0*x0, q1 = x1*x1, q2 = x2*x2, q3 = x3*x3, q4 = x4*x4, q5 = x5*x5;
    v2f aq = q1 + q2, bq = q3 + q4;
    h.hxx[0] = q0 + aq;  h.hxx[1] = aq + q3;
    h.hxx[2] = q2 + bq;  h.hxx[3] = bq + q5;

    float m0 = x0.x*x0.y, m1 = x1.x*x1.y, m2 = x2.x*x2.y,
          m3 = x3.x*x3.y, m4 = x4.x*x4.y, m5 = x5.x*x5.y;
    float am = m1 + m2, bm = m3 + m4;
    h.hpt[0] = m0 + am;  h.hpt[1] = am + m3;
    h.hpt[2] = m2 + bm;  h.hpt[3] = bm + m5;
    return h;
}

__device__ __forceinline__ void emit_row(
    float* __restrict__ out, size_t base, int row, int col0,
    const RowH& A, const RowH& B, const RowH& C)
{
    const float C1 = 1e-4f;    // 0.01^2
    const float C2 = 9e-4f;    // 0.03^2
    const float inv9 = 1.0f / 9.0f;

    v4f rv;
    #pragma unroll
    for (int j = 0; j < 4; ++j) {
        v2f sx  = A.hx[j]  + B.hx[j]  + C.hx[j];
        v2f sxx = A.hxx[j] + B.hxx[j] + C.hxx[j];
        float spt = A.hpt[j] + B.hpt[j] + C.hpt[j];

        v2f u  = sx * inv9;
        v2f uu = u * u;
        v2f sig = sxx * inv9 - uu;
        float upt   = u.x * u.y;
        float sigco = fmaf(spt, inv9, -upt);

        float num = fmaf(2.f, upt, C1) * fmaf(2.f, sigco, C2);
        float den = (uu.x + uu.y + C1) * (sig.x + sig.y + C2);
        float q = num * __builtin_amdgcn_rcpf(den);
        rv[j] = fminf(fmaxf(fmaf(q, -0.5f, 0.5f), 0.f), 1.f);
    }
    __builtin_nontemporal_store(rv, (v4f*)(out + base + (size_t)row * IMG_W + col0));
}

__global__ __launch_bounds__(NLX * TY) void ssim_kernel(
    const float* __restrict__ pred,
    const float* __restrict__ target,
    float* __restrict__ out)
{
    const int lx   = threadIdx.x;            // 0..127
    const int lane = lx & 63;
    const int col0 = 4 * lx;
    const size_t base = (size_t)blockIdx.z * (IMG_H * IMG_W);
    const int y0 = (blockIdx.y * TY + threadIdx.y) * RPT;

    const bool needL = (lane == 0)  && (col0 != 0);
    const bool needR = (lane == 63) && (col0 + 4 != IMG_W);
    const int  eoff  = needL ? (col0 - 1) : (needR ? (col0 + 4) : col0); // interior: harmless self-line

    Raw raw0, raw1, raw2, raw3;
    RowH h0, h1, h2;

    // prologue: rows k=0..3 (ry = y0-1 .. y0+2), 16 loads in flight
    ISSUE(0, y0 - 1); ISSUE(1, y0); ISSUE(2, y0 + 1); ISSUE(3, y0 + 2);
    WAITV(12); h0 = reduce_row(raw0, lane, col0);
    WAITV(8);  h1 = reduce_row(raw1, lane, col0);

    // steady state: issue row k=r+4, consume row k=r+2 (2 rows = 8 loads stay in flight)
    ISSUE(0, y0 + 3); WAITV(8); h2 = reduce_row(raw2, lane, col0);
    emit_row(out, base, y0 + 0, col0, h0, h1, h2);
    ISSUE(1, y0 + 4); WAITV(8); h0 = reduce_row(raw3, lane, col0);
    emit_row(out, base, y0 + 1, col0, h1, h2, h0);
    ISSUE(2, y0 + 5); WAITV(8); h1 = reduce_row(raw0, lane, col0);
    emit_row(out, base, y0 + 2, col0, h2, h0, h1);
    ISSUE(3, y0 + 6); WAITV(8); h2 = reduce_row(raw1, lane, col0);
    emit_row(out, base, y0 + 3, col0, h0, h1, h2);
    ISSUE(0, y0 + 7); WAITV(8); h0 = reduce_row(raw2, lane, col0);
    emit_row(out, base, y0 + 4, col0, h1, h2, h0);
    ISSUE(1, y0 + 8); WAITV(8); h1 = reduce_row(raw3, lane, col0);
    emit_row(out, base, y0 + 5, col0, h2, h0, h1);
    /* tail */        WAITV(4); h2 = reduce_row(raw0, lane, col0);
    emit_row(out, base, y0 + 6, col0, h0, h1, h2);
                      WAITV(0); h0 = reduce_row(raw1, lane, col0);
    emit_row(out, base, y0 + 7, col0, h1, h2, h0);
}

extern "C" void kernel_launch(void* const* d_in, const int* in_sizes, int n_in,
                              void* d_out, int out_size, void* d_ws, size_t ws_size,
                              hipStream_t stream) {
    const float* pred   = (const float*)d_in[0];
    const float* target = (const float*)d_in[1];
    float* out = (float*)d_out;

    const int planes = in_sizes[0] / (IMG_H * IMG_W);   // 32*3 = 96

    dim3 block(NLX, TY);                                 // 256 threads
    dim3 grid(1, IMG_H / (TY * RPT), planes);            // (1, 24, 96)
    ssim_kernel<<<grid, block, 0, stream>>>(pred, target, out);
}